// Round 1
// baseline (1616.045 us; speedup 1.0000x reference)
//
#include <hip/hip_runtime.h>
#include <math.h>

#define DIMD 1024
#define NH 16
#define DH 64
#define BB 2
#define SS 2048
#define M_TOTAL (BB * SS) /* 4096 */

// ---------------------------------------------------------------------------
// Projection GEMM: out = x @ W + b, scattered into (B,H,S,Dh) layout.
// grid = (M/64, N/64, 3 [q,k,v]), block = 256 threads (16x16), 4x4 microtile.
// ---------------------------------------------------------------------------
__global__ __launch_bounds__(256) void proj_kernel(
    const float* __restrict__ x,
    const float* __restrict__ Wq, const float* __restrict__ bq,
    const float* __restrict__ Wk, const float* __restrict__ bk,
    const float* __restrict__ Wv, const float* __restrict__ bv,
    float* __restrict__ Q, float* __restrict__ K, float* __restrict__ V)
{
    const float* W;
    const float* bias;
    float* out;
    if (blockIdx.z == 0)      { W = Wq; bias = bq; out = Q; }
    else if (blockIdx.z == 1) { W = Wk; bias = bk; out = K; }
    else                      { W = Wv; bias = bv; out = V; }

    // stride 68 (multiple of 4 -> float4-aligned rows; 68%32=4 -> only 2-way
    // LDS bank aliasing, which is free on CDNA4)
    __shared__ float As[16][68]; // [k][m]
    __shared__ float Bs[16][68]; // [k][n]

    const int tid = threadIdx.x;
    const int tx = tid & 15;      // n-direction
    const int ty = tid >> 4;      // m-direction
    const int m0 = blockIdx.x * 64;
    const int n0 = blockIdx.y * 64;

    // A loader: thread -> (row am, 4 consecutive k at ak)
    const int am = tid >> 2;          // 0..63
    const int ak = (tid & 3) * 4;     // 0,4,8,12
    // B loader: thread -> (k row bkr, 4 consecutive n at bn)
    const int bkr = tid >> 4;         // 0..15
    const int bn  = (tid & 15) * 4;   // 0..60

    float c[4][4] = {{0.f}};

    for (int k0 = 0; k0 < DIMD; k0 += 16) {
        float4 av  = *(const float4*)&x[(size_t)(m0 + am) * DIMD + k0 + ak];
        float4 bv4 = *(const float4*)&W[(size_t)(k0 + bkr) * DIMD + n0 + bn];
        As[ak + 0][am] = av.x;
        As[ak + 1][am] = av.y;
        As[ak + 2][am] = av.z;
        As[ak + 3][am] = av.w;
        *(float4*)&Bs[bkr][bn] = bv4;
        __syncthreads();

#pragma unroll
        for (int kk = 0; kk < 16; ++kk) {
            float4 a4 = *(const float4*)&As[kk][ty * 4];
            float4 b4 = *(const float4*)&Bs[kk][tx * 4];
            float a[4] = {a4.x, a4.y, a4.z, a4.w};
            float b[4] = {b4.x, b4.y, b4.z, b4.w};
#pragma unroll
            for (int i = 0; i < 4; ++i)
#pragma unroll
                for (int j = 0; j < 4; ++j)
                    c[i][j] += a[i] * b[j];
        }
        __syncthreads();
    }

    // epilogue: scatter into (B,H,S,Dh). Tile spans exactly one head
    // (n0 is a multiple of 64 and tile width is 64 -> h = blockIdx.y).
#pragma unroll
    for (int i = 0; i < 4; ++i) {
        const int row = m0 + ty * 4 + i;       // 0..4095
        const int b   = row >> 11;             // /2048
        const int s   = row & 2047;
#pragma unroll
        for (int j = 0; j < 4; ++j) {
            const int n = n0 + tx * 4 + j;
            const int h = n >> 6;
            const int d = n & 63;
            out[((((size_t)b * NH + h) * SS + s) << 6) + d] = c[i][j] + bias[n];
        }
    }
}

// ---------------------------------------------------------------------------
// Flash-style attention: one thread per query. q/acc live in VGPRs, K/V tiles
// of 64 keys staged in LDS, all lanes read identical LDS addresses (broadcast).
// grid = (S/128, B*H), block = 128.
// ---------------------------------------------------------------------------
__global__ __launch_bounds__(128) void attn_kernel(
    const float* __restrict__ Q, const float* __restrict__ K,
    const float* __restrict__ V, const int* __restrict__ mask,
    float* __restrict__ out)
{
    const int bh = blockIdx.y;      // 0..31
    const int b  = bh >> 4;
    const int h  = bh & 15;
    const int qi = blockIdx.x * 128 + threadIdx.x; // query index in S

    const float* Qb = Q + (size_t)bh * SS * DH;
    const float* Kb = K + (size_t)bh * SS * DH;
    const float* Vb = V + (size_t)bh * SS * DH;

    __shared__ float Ks[64 * 64];
    __shared__ float Vs[64 * 64];
    __shared__ float mb[64];

    float q[64];
#pragma unroll
    for (int d4 = 0; d4 < 16; ++d4) {
        float4 t = *(const float4*)&Qb[(size_t)qi * DH + d4 * 4];
        q[4 * d4 + 0] = t.x;
        q[4 * d4 + 1] = t.y;
        q[4 * d4 + 2] = t.z;
        q[4 * d4 + 3] = t.w;
    }

    float acc[64];
#pragma unroll
    for (int d = 0; d < 64; ++d) acc[d] = 0.f;
    float mval = -1e30f;
    float l = 0.f;

    for (int t0 = 0; t0 < SS; t0 += 64) {
        // stage 64 keys + 64 values (4096 floats each) with 128 threads
        const float4* Ksrc = (const float4*)&Kb[(size_t)t0 * DH];
        const float4* Vsrc = (const float4*)&Vb[(size_t)t0 * DH];
        float4* Kd = (float4*)Ks;
        float4* Vd = (float4*)Vs;
#pragma unroll
        for (int i = 0; i < 8; ++i) {
            const int idx = threadIdx.x + i * 128;
            Kd[idx] = Ksrc[idx];
            Vd[idx] = Vsrc[idx];
        }
        if (threadIdx.x < 64) {
            mb[threadIdx.x] =
                -10000.f * (1.f - (float)mask[b * SS + t0 + threadIdx.x]);
        }
        __syncthreads();

#pragma unroll 1
        for (int cch = 0; cch < 8; ++cch) { // chunks of 8 keys
            float s[8];
#pragma unroll
            for (int j = 0; j < 8; ++j) {
                const int tt = cch * 8 + j;
                const float4* kr = (const float4*)&Ks[tt * 64];
                float d0 = 0.f, d1 = 0.f, d2 = 0.f, d3 = 0.f;
#pragma unroll
                for (int d4 = 0; d4 < 16; ++d4) {
                    float4 kv = kr[d4];
                    d0 += q[4 * d4 + 0] * kv.x;
                    d1 += q[4 * d4 + 1] * kv.y;
                    d2 += q[4 * d4 + 2] * kv.z;
                    d3 += q[4 * d4 + 3] * kv.w;
                }
                s[j] = (d0 + d1 + d2 + d3) * 0.125f + mb[tt];
            }
            float mnew = mval;
#pragma unroll
            for (int j = 0; j < 8; ++j) mnew = fmaxf(mnew, s[j]);
            const float alpha = __expf(mval - mnew);
            mval = mnew;
            l *= alpha;
#pragma unroll
            for (int d = 0; d < 64; ++d) acc[d] *= alpha;
#pragma unroll
            for (int j = 0; j < 8; ++j) {
                const int tt = cch * 8 + j;
                const float p = __expf(s[j] - mval);
                l += p;
                const float4* vr = (const float4*)&Vs[tt * 64];
#pragma unroll
                for (int d4 = 0; d4 < 16; ++d4) {
                    float4 vv = vr[d4];
                    acc[4 * d4 + 0] += p * vv.x;
                    acc[4 * d4 + 1] += p * vv.y;
                    acc[4 * d4 + 2] += p * vv.z;
                    acc[4 * d4 + 3] += p * vv.w;
                }
            }
        }
        __syncthreads();
    }

    const float inv = 1.f / l;
    float* op = out + ((size_t)b * SS + qi) * DIMD + h * DH;
#pragma unroll
    for (int d4 = 0; d4 < 16; ++d4) {
        float4 r;
        r.x = acc[4 * d4 + 0] * inv;
        r.y = acc[4 * d4 + 1] * inv;
        r.z = acc[4 * d4 + 2] * inv;
        r.w = acc[4 * d4 + 3] * inv;
        *(float4*)&op[d4 * 4] = r;
    }
}

extern "C" void kernel_launch(void* const* d_in, const int* in_sizes, int n_in,
                              void* d_out, int out_size, void* d_ws, size_t ws_size,
                              hipStream_t stream) {
    const float* x  = (const float*)d_in[0];
    const int* mask = (const int*)d_in[1];
    const float* Wq = (const float*)d_in[2];
    const float* bq = (const float*)d_in[3];
    const float* Wk = (const float*)d_in[4];
    const float* bk = (const float*)d_in[5];
    const float* Wv = (const float*)d_in[6];
    const float* bv = (const float*)d_in[7];
    float* out = (float*)d_out;

    // workspace: Q, K, V in (B,H,S,Dh) layout, 16 MB each (48 MB total)
    float* Q = (float*)d_ws;
    float* K = Q + (size_t)M_TOTAL * DIMD;
    float* V = K + (size_t)M_TOTAL * DIMD;

    dim3 gp(M_TOTAL / 64, DIMD / 64, 3);
    proj_kernel<<<gp, 256, 0, stream>>>(x, Wq, bq, Wk, bk, Wv, bv, Q, K, V);

    dim3 ga(SS / 128, BB * NH);
    attn_kernel<<<ga, 128, 0, stream>>>(Q, K, V, mask, out);
}

// Round 3
// 546.667 us; speedup vs baseline: 2.9562x; 2.9562x over previous
//
#include <hip/hip_runtime.h>
#include <math.h>

#define DIMD 1024
#define NH 16
#define DH 64
#define BB 2
#define SS 2048
#define M_TOTAL (BB * SS) /* 4096 */

typedef _Float16 half8 __attribute__((ext_vector_type(8)));
typedef float floatx4 __attribute__((ext_vector_type(4)));

// ---------------------------------------------------------------------------
// Projection GEMM: out = x @ W + b (fp32 compute), scattered into (B,H,S,Dh)
// layout as fp16 for the MFMA attention kernel.
// grid = (M/64, N/64, 3 [q,k,v]), block = 256 threads (16x16), 4x4 microtile.
// ---------------------------------------------------------------------------
__global__ __launch_bounds__(256) void proj_kernel(
    const float* __restrict__ x,
    const float* __restrict__ Wq, const float* __restrict__ bq,
    const float* __restrict__ Wk, const float* __restrict__ bk,
    const float* __restrict__ Wv, const float* __restrict__ bv,
    _Float16* __restrict__ Q, _Float16* __restrict__ K, _Float16* __restrict__ V)
{
    const float* W;
    const float* bias;
    _Float16* out;
    if (blockIdx.z == 0)      { W = Wq; bias = bq; out = Q; }
    else if (blockIdx.z == 1) { W = Wk; bias = bk; out = K; }
    else                      { W = Wv; bias = bv; out = V; }

    __shared__ float As[16][68]; // [k][m], stride 68 -> 2-way bank alias (free)
    __shared__ float Bs[16][68]; // [k][n]

    const int tid = threadIdx.x;
    const int tx = tid & 15;      // n-direction
    const int ty = tid >> 4;      // m-direction
    const int m0 = blockIdx.x * 64;
    const int n0 = blockIdx.y * 64;

    const int am = tid >> 2;          // 0..63
    const int ak = (tid & 3) * 4;     // 0,4,8,12
    const int bkr = tid >> 4;         // 0..15
    const int bn  = (tid & 15) * 4;   // 0..60

    float c[4][4] = {{0.f}};

    for (int k0 = 0; k0 < DIMD; k0 += 16) {
        float4 av  = *(const float4*)&x[(size_t)(m0 + am) * DIMD + k0 + ak];
        float4 bv4 = *(const float4*)&W[(size_t)(k0 + bkr) * DIMD + n0 + bn];
        As[ak + 0][am] = av.x;
        As[ak + 1][am] = av.y;
        As[ak + 2][am] = av.z;
        As[ak + 3][am] = av.w;
        *(float4*)&Bs[bkr][bn] = bv4;
        __syncthreads();

#pragma unroll
        for (int kk = 0; kk < 16; ++kk) {
            float4 a4 = *(const float4*)&As[kk][ty * 4];
            float4 b4 = *(const float4*)&Bs[kk][tx * 4];
            float a[4] = {a4.x, a4.y, a4.z, a4.w};
            float b[4] = {b4.x, b4.y, b4.z, b4.w};
#pragma unroll
            for (int i = 0; i < 4; ++i)
#pragma unroll
                for (int j = 0; j < 4; ++j)
                    c[i][j] += a[i] * b[j];
        }
        __syncthreads();
    }

    // scatter into (B,H,S,Dh) as fp16; tile spans exactly one head
#pragma unroll
    for (int i = 0; i < 4; ++i) {
        const int row = m0 + ty * 4 + i;       // 0..4095
        const int b   = row >> 11;             // /2048
        const int s   = row & 2047;
#pragma unroll
        for (int j = 0; j < 4; ++j) {
            const int n = n0 + tx * 4 + j;
            const int h = n >> 6;
            const int d = n & 63;
            out[((((size_t)b * NH + h) * SS + s) << 6) + d] =
                (_Float16)(c[i][j] + bias[n]);
        }
    }
}

// ---------------------------------------------------------------------------
// MFMA flash attention (fp16 inputs, fp32 accumulate).
// Block: 256 threads = 4 waves; 64 queries/block (16 per wave); K-tile = 64.
// mfma_f32_16x16x32_f16 for QK^T and PV. P goes C-layout -> LDS -> A-layout,
// with an explicit __syncthreads() between write and read: the A-fragment
// read pulls rows written by OTHER quads of the wave; do not rely on
// unordered same-wave DS visibility. (Round-2 post-timing divergence.)
// grid = (S/64, B*H), block = 256.
// ---------------------------------------------------------------------------
__global__ __launch_bounds__(256) void attn_kernel(
    const _Float16* __restrict__ Q, const _Float16* __restrict__ K,
    const _Float16* __restrict__ V, const int* __restrict__ mask,
    float* __restrict__ out)
{
    const int bh = blockIdx.y;      // 0..31
    const int b  = bh >> 4;
    const int h  = bh & 15;
    const int q0 = blockIdx.x * 64;

    const int tid  = threadIdx.x;
    const int wave = tid >> 6;
    const int lane = tid & 63;
    const int quad = lane >> 4;
    const int l16  = lane & 15;

    // stride 72 halfs = 144 B: 16B-aligned rows, 4-bank row shift
    __shared__ _Float16 Qs[64][72];      // [q][d]
    __shared__ _Float16 Ks[64][72];      // [t][d]
    __shared__ _Float16 Vt[64][72];      // [d][t]  (transposed at staging)
    __shared__ _Float16 Ps[4][16][72];   // per-wave P [q][t]
    __shared__ float mb[64];

    const _Float16* Qb = Q + (size_t)bh * SS * DH;
    const _Float16* Kb = K + (size_t)bh * SS * DH;
    const _Float16* Vb = V + (size_t)bh * SS * DH;

    // ---- stage Q tile (once): 512 x 16B units ----
#pragma unroll
    for (int u = tid; u < 512; u += 256) {
        const int row = u >> 3, off = (u & 7) * 8;
        *(uint4*)&Qs[row][off] = *(const uint4*)&Qb[(size_t)(q0 + row) * DH + off];
    }
    __syncthreads();

    // Q A-fragments (reused every k-tile)
    half8 qa0 = *(const half8*)&Qs[wave * 16 + l16][quad * 8];
    half8 qa1 = *(const half8*)&Qs[wave * 16 + l16][quad * 8 + 32];

    floatx4 O[4];                 // [dtile] -> 16 queries x 64 dims
#pragma unroll
    for (int dt = 0; dt < 4; ++dt) O[dt] = (floatx4){0.f, 0.f, 0.f, 0.f};
    float mrow[4], lrow[4];
#pragma unroll
    for (int r = 0; r < 4; ++r) { mrow[r] = -1e30f; lrow[r] = 0.f; }

    for (int t0 = 0; t0 < SS; t0 += 64) {
        __syncthreads(); // previous tile's LDS reads complete before overwrite

        // stage K tile (natural layout), coalesced 16B units
#pragma unroll
        for (int u = tid; u < 512; u += 256) {
            const int row = u >> 3, off = (u & 7) * 8;
            *(uint4*)&Ks[row][off] =
                *(const uint4*)&Kb[(size_t)(t0 + row) * DH + off];
        }
        // stage V tile transposed: lane sweeps t (scalar b16 writes -> 2-way, free)
#pragma unroll
        for (int u = tid; u < 512; u += 256) {
            const int t = u & 63, d0 = (u >> 6) * 8;
            union { uint4 u4; _Float16 hv[8]; } tmp;
            tmp.u4 = *(const uint4*)&Vb[(size_t)(t0 + t) * DH + d0];
#pragma unroll
            for (int k = 0; k < 8; ++k) Vt[d0 + k][t] = tmp.hv[k];
        }
        if (tid < 64)
            mb[tid] = -10000.f * (1.f - (float)mask[b * SS + t0 + tid]);
        __syncthreads();

        // ---- QK^T: S[16q][64t] = 4 ntiles x 2 k-chunks of MFMA ----
        floatx4 Sacc[4];
#pragma unroll
        for (int nt = 0; nt < 4; ++nt) {
            Sacc[nt] = (floatx4){0.f, 0.f, 0.f, 0.f};
            half8 kb0 = *(const half8*)&Ks[nt * 16 + l16][quad * 8];
            half8 kb1 = *(const half8*)&Ks[nt * 16 + l16][quad * 8 + 32];
            Sacc[nt] = __builtin_amdgcn_mfma_f32_16x16x32_f16(qa0, kb0, Sacc[nt], 0, 0, 0);
            Sacc[nt] = __builtin_amdgcn_mfma_f32_16x16x32_f16(qa1, kb1, Sacc[nt], 0, 0, 0);
        }

        // ---- scores + mask bias ----
        float sc[4][4];
#pragma unroll
        for (int nt = 0; nt < 4; ++nt) {
            const float bias = mb[l16 + nt * 16];
#pragma unroll
            for (int r = 0; r < 4; ++r)
                sc[nt][r] = Sacc[nt][r] * 0.125f + bias;
        }

        // ---- online softmax (row r lives on the 16 lanes of this quad) ----
        float tmax[4];
#pragma unroll
        for (int r = 0; r < 4; ++r) {
            tmax[r] = fmaxf(fmaxf(sc[0][r], sc[1][r]), fmaxf(sc[2][r], sc[3][r]));
        }
#pragma unroll
        for (int m = 1; m < 16; m <<= 1) {
#pragma unroll
            for (int r = 0; r < 4; ++r)
                tmax[r] = fmaxf(tmax[r], __shfl_xor(tmax[r], m));
        }
        float alpha[4];
#pragma unroll
        for (int r = 0; r < 4; ++r) {
            const float mn = fmaxf(mrow[r], tmax[r]);
            alpha[r] = __expf(mrow[r] - mn);
            mrow[r]  = mn;
            lrow[r] *= alpha[r];
        }
#pragma unroll
        for (int dt = 0; dt < 4; ++dt)
#pragma unroll
            for (int r = 0; r < 4; ++r) O[dt][r] *= alpha[r];

        // ---- P = exp(s - m); write to per-wave LDS in [q][t] ----
        float rsum[4] = {0.f, 0.f, 0.f, 0.f};
#pragma unroll
        for (int nt = 0; nt < 4; ++nt) {
#pragma unroll
            for (int r = 0; r < 4; ++r) {
                const float p = __expf(sc[nt][r] - mrow[r]);
                rsum[r] += p;
                Ps[wave][quad * 4 + r][l16 + nt * 16] = (_Float16)p;
            }
        }
#pragma unroll
        for (int m = 1; m < 16; m <<= 1) {
#pragma unroll
            for (int r = 0; r < 4; ++r) rsum[r] += __shfl_xor(rsum[r], m);
        }
#pragma unroll
        for (int r = 0; r < 4; ++r) lrow[r] += rsum[r];

        // make quad-crossing Ps writes visible before A-fragment reads
        __syncthreads();

        // ---- PV: O[16q][64d] += P @ V ----
        half8 pa0 = *(const half8*)&Ps[wave][l16][quad * 8];
        half8 pa1 = *(const half8*)&Ps[wave][l16][quad * 8 + 32];
#pragma unroll
        for (int dt = 0; dt < 4; ++dt) {
            half8 vb0 = *(const half8*)&Vt[dt * 16 + l16][quad * 8];
            half8 vb1 = *(const half8*)&Vt[dt * 16 + l16][quad * 8 + 32];
            O[dt] = __builtin_amdgcn_mfma_f32_16x16x32_f16(pa0, vb0, O[dt], 0, 0, 0);
            O[dt] = __builtin_amdgcn_mfma_f32_16x16x32_f16(pa1, vb1, O[dt], 0, 0, 0);
        }
    }

    // ---- epilogue: O /= l, store fp32 ----
#pragma unroll
    for (int r = 0; r < 4; ++r) {
        const float inv = 1.f / lrow[r];
        const int q = q0 + wave * 16 + quad * 4 + r;
        float* op = out + ((size_t)(b * SS + q)) * DIMD + h * DH;
#pragma unroll
        for (int dt = 0; dt < 4; ++dt)
            op[dt * 16 + l16] = O[dt][r] * inv;
    }
}

extern "C" void kernel_launch(void* const* d_in, const int* in_sizes, int n_in,
                              void* d_out, int out_size, void* d_ws, size_t ws_size,
                              hipStream_t stream) {
    const float* x  = (const float*)d_in[0];
    const int* mask = (const int*)d_in[1];
    const float* Wq = (const float*)d_in[2];
    const float* bq = (const float*)d_in[3];
    const float* Wk = (const float*)d_in[4];
    const float* bk = (const float*)d_in[5];
    const float* Wv = (const float*)d_in[6];
    const float* bv = (const float*)d_in[7];
    float* out = (float*)d_out;

    // workspace: Q, K, V fp16 in (B,H,S,Dh) layout, 8 MB each
    _Float16* Q = (_Float16*)d_ws;
    _Float16* K = Q + (size_t)M_TOTAL * DIMD;
    _Float16* V = K + (size_t)M_TOTAL * DIMD;

    dim3 gp(M_TOTAL / 64, DIMD / 64, 3);
    proj_kernel<<<gp, 256, 0, stream>>>(x, Wq, bq, Wk, bk, Wv, bv, Q, K, V);

    dim3 ga(SS / 64, BB * NH);
    attn_kernel<<<ga, 256, 0, stream>>>(Q, K, V, mask, out);
}

// Round 4
// 260.242 us; speedup vs baseline: 6.2098x; 2.1006x over previous
//
#include <hip/hip_runtime.h>
#include <math.h>

#define DIMD 1024
#define NH 16
#define DH 64
#define BB 2
#define SS 2048
#define M_TOTAL (BB * SS) /* 4096 */

typedef _Float16 half8 __attribute__((ext_vector_type(8)));
typedef _Float16 half4v __attribute__((ext_vector_type(4)));
typedef float floatx4 __attribute__((ext_vector_type(4)));

// async 16B global->LDS. LDS dest is wave-uniform base + lane*16 (m104/m108):
// pass the SAME base for all lanes of a wave; lane data lands at base+lane*16.
__device__ __forceinline__ void load16_to_lds(const void* g, void* l) {
    __builtin_amdgcn_global_load_lds(
        (const __attribute__((address_space(1))) void*)g,
        (__attribute__((address_space(3))) void*)l, 16, 0, 0);
}

// ---------------------------------------------------------------------------
// x fp32 -> fp16, same [m][k] layout. grid 4096 x 256 thr, one float4/thread.
// ---------------------------------------------------------------------------
__global__ __launch_bounds__(256) void cvt_x_kernel(
    const float* __restrict__ x, _Float16* __restrict__ xh)
{
    const int i = blockIdx.x * 256 + threadIdx.x; // float4 index
    float4 v = ((const float4*)x)[i];
    half4v h = {(_Float16)v.x, (_Float16)v.y, (_Float16)v.z, (_Float16)v.w};
    *(half4v*)&xh[(size_t)i * 4] = h;
}

// ---------------------------------------------------------------------------
// W [k][n] fp32 -> Wt [n][k] fp16 (transpose via LDS 32x32 tile).
// grid (32,32,3) x 256 thr.
// ---------------------------------------------------------------------------
__global__ __launch_bounds__(256) void cvt_wt_kernel(
    const float* __restrict__ Wq, const float* __restrict__ Wk,
    const float* __restrict__ Wv, _Float16* __restrict__ Wt)
{
    const float* W = blockIdx.z == 0 ? Wq : (blockIdx.z == 1 ? Wk : Wv);
    _Float16* o = Wt + (size_t)blockIdx.z * DIMD * DIMD;
    __shared__ _Float16 Ls[32][34]; // stride 34: 17-bank row shift
    const int k0 = blockIdx.x * 32, n0 = blockIdx.y * 32;
    const int tid = threadIdx.x;
    const int r = tid >> 3, c4 = (tid & 7) * 4;

    float4 v = *(const float4*)&W[(size_t)(k0 + r) * DIMD + n0 + c4];
    Ls[r][c4 + 0] = (_Float16)v.x;
    Ls[r][c4 + 1] = (_Float16)v.y;
    Ls[r][c4 + 2] = (_Float16)v.z;
    Ls[r][c4 + 3] = (_Float16)v.w;
    __syncthreads();

    half4v h = {Ls[c4 + 0][r], Ls[c4 + 1][r], Ls[c4 + 2][r], Ls[c4 + 3][r]};
    *(half4v*)&o[(size_t)(n0 + r) * DIMD + k0 + c4] = h;
}

// ---------------------------------------------------------------------------
// MFMA projection GEMM: C = xh @ Wt^T (+bias), scattered to (B,H,S,Dh) fp16.
// 128x128 tile, BK=64, 4 waves, each wave 64x64 via 4x4 16x16x32 mfma.
// Staging: global_load_lds 16B, XOR-swizzled k-chunks (no padding allowed
// with DMA; swizzle spreads frag reads to the 8-lanes/bank-group floor).
// grid (32, 8, 3) x 256 thr.
// ---------------------------------------------------------------------------
__global__ __launch_bounds__(256) void proj_gemm(
    const _Float16* __restrict__ xh, const _Float16* __restrict__ Wt,
    const float* __restrict__ bq, const float* __restrict__ bk,
    const float* __restrict__ bv,
    _Float16* __restrict__ Q, _Float16* __restrict__ K, _Float16* __restrict__ V)
{
    const int z = blockIdx.z;
    const float* bias = z == 0 ? bq : (z == 1 ? bk : bv);
    _Float16* out = z == 0 ? Q : (z == 1 ? K : V);
    const _Float16* Wz = Wt + (size_t)z * DIMD * DIMD;

    __shared__ _Float16 Ah[128 * 64]; // [row][k], swizzled chunks
    __shared__ _Float16 Bh[128 * 64]; // [n][k], swizzled chunks

    const int tid = threadIdx.x;
    const int wave = tid >> 6, lane = tid & 63;
    const int quad = lane >> 4, l16 = lane & 15;
    const int wm = (wave >> 1) * 64, wn = (wave & 1) * 64;
    const int m0 = blockIdx.x * 128, n0 = blockIdx.y * 128;
    const int sw = l16 & 7;

    floatx4 acc[4][4];
#pragma unroll
    for (int i = 0; i < 4; ++i)
#pragma unroll
        for (int j = 0; j < 4; ++j) acc[i][j] = (floatx4){0.f, 0.f, 0.f, 0.f};

    for (int k0 = 0; k0 < DIMD; k0 += 64) {
        __syncthreads(); // prior frag reads done before DMA overwrites
#pragma unroll
        for (int it = 0; it < 4; ++it) {
            const int u = it * 256 + tid;
            const int row = u >> 3;
            const int gc = (u & 7) ^ (row & 7); // LDS slot u&7 holds chunk gc
            load16_to_lds(&xh[(size_t)(m0 + row) * DIMD + k0 + gc * 8],
                          &Ah[(size_t)(it * 256 + wave * 64) * 8]);
        }
#pragma unroll
        for (int it = 0; it < 4; ++it) {
            const int u = it * 256 + tid;
            const int row = u >> 3;
            const int gc = (u & 7) ^ (row & 7);
            load16_to_lds(&Wz[(size_t)(n0 + row) * DIMD + k0 + gc * 8],
                          &Bh[(size_t)(it * 256 + wave * 64) * 8]);
        }
        __syncthreads(); // drains vmcnt (compiler emits vmcnt(0) before barrier)

#pragma unroll
        for (int kc = 0; kc < 2; ++kc) {
            const int coff = ((quad + kc * 4) ^ sw) * 8;
            half8 af[4], bf[4];
#pragma unroll
            for (int mt = 0; mt < 4; ++mt)
                af[mt] = *(const half8*)&Ah[(wm + mt * 16 + l16) * 64 + coff];
#pragma unroll
            for (int nt = 0; nt < 4; ++nt)
                bf[nt] = *(const half8*)&Bh[(wn + nt * 16 + l16) * 64 + coff];
#pragma unroll
            for (int mt = 0; mt < 4; ++mt)
#pragma unroll
                for (int nt = 0; nt < 4; ++nt)
                    acc[mt][nt] = __builtin_amdgcn_mfma_f32_16x16x32_f16(
                        af[mt], bf[nt], acc[mt][nt], 0, 0, 0);
        }
    }

    // epilogue: +bias, fp16, scatter to (B,H,S,Dh). C/D: row=quad*4+r, col=l16
#pragma unroll
    for (int nt = 0; nt < 4; ++nt) {
        const int n = n0 + wn + nt * 16 + l16;
        const float bn = bias[n];
        const int h = n >> 6, d = n & 63;
#pragma unroll
        for (int mt = 0; mt < 4; ++mt) {
#pragma unroll
            for (int r = 0; r < 4; ++r) {
                const int m = m0 + wm + mt * 16 + quad * 4 + r;
                const int b = m >> 11, s = m & 2047;
                out[((((size_t)b * NH + h) * SS + s) << 6) + d] =
                    (_Float16)(acc[mt][nt][r] + bn);
            }
        }
    }
}

// ---------------------------------------------------------------------------
// MFMA flash attention (fp16 inputs, fp32 accumulate). Unchanged from R3.
// grid = (S/64, B*H), block = 256.
// ---------------------------------------------------------------------------
__global__ __launch_bounds__(256) void attn_kernel(
    const _Float16* __restrict__ Q, const _Float16* __restrict__ K,
    const _Float16* __restrict__ V, const int* __restrict__ mask,
    float* __restrict__ out)
{
    const int bh = blockIdx.y;      // 0..31
    const int b  = bh >> 4;
    const int h  = bh & 15;
    const int q0 = blockIdx.x * 64;

    const int tid  = threadIdx.x;
    const int wave = tid >> 6;
    const int lane = tid & 63;
    const int quad = lane >> 4;
    const int l16  = lane & 15;

    __shared__ _Float16 Qs[64][72];      // [q][d]
    __shared__ _Float16 Ks[64][72];      // [t][d]
    __shared__ _Float16 Vt[64][72];      // [d][t]  (transposed at staging)
    __shared__ _Float16 Ps[4][16][72];   // per-wave P [q][t]
    __shared__ float mb[64];

    const _Float16* Qb = Q + (size_t)bh * SS * DH;
    const _Float16* Kb = K + (size_t)bh * SS * DH;
    const _Float16* Vb = V + (size_t)bh * SS * DH;

#pragma unroll
    for (int u = tid; u < 512; u += 256) {
        const int row = u >> 3, off = (u & 7) * 8;
        *(uint4*)&Qs[row][off] = *(const uint4*)&Qb[(size_t)(q0 + row) * DH + off];
    }
    __syncthreads();

    half8 qa0 = *(const half8*)&Qs[wave * 16 + l16][quad * 8];
    half8 qa1 = *(const half8*)&Qs[wave * 16 + l16][quad * 8 + 32];

    floatx4 O[4];
#pragma unroll
    for (int dt = 0; dt < 4; ++dt) O[dt] = (floatx4){0.f, 0.f, 0.f, 0.f};
    float mrow[4], lrow[4];
#pragma unroll
    for (int r = 0; r < 4; ++r) { mrow[r] = -1e30f; lrow[r] = 0.f; }

    for (int t0 = 0; t0 < SS; t0 += 64) {
        __syncthreads();

#pragma unroll
        for (int u = tid; u < 512; u += 256) {
            const int row = u >> 3, off = (u & 7) * 8;
            *(uint4*)&Ks[row][off] =
                *(const uint4*)&Kb[(size_t)(t0 + row) * DH + off];
        }
#pragma unroll
        for (int u = tid; u < 512; u += 256) {
            const int t = u & 63, d0 = (u >> 6) * 8;
            union { uint4 u4; _Float16 hv[8]; } tmp;
            tmp.u4 = *(const uint4*)&Vb[(size_t)(t0 + t) * DH + d0];
#pragma unroll
            for (int k = 0; k < 8; ++k) Vt[d0 + k][t] = tmp.hv[k];
        }
        if (tid < 64)
            mb[tid] = -10000.f * (1.f - (float)mask[b * SS + t0 + tid]);
        __syncthreads();

        floatx4 Sacc[4];
#pragma unroll
        for (int nt = 0; nt < 4; ++nt) {
            Sacc[nt] = (floatx4){0.f, 0.f, 0.f, 0.f};
            half8 kb0 = *(const half8*)&Ks[nt * 16 + l16][quad * 8];
            half8 kb1 = *(const half8*)&Ks[nt * 16 + l16][quad * 8 + 32];
            Sacc[nt] = __builtin_amdgcn_mfma_f32_16x16x32_f16(qa0, kb0, Sacc[nt], 0, 0, 0);
            Sacc[nt] = __builtin_amdgcn_mfma_f32_16x16x32_f16(qa1, kb1, Sacc[nt], 0, 0, 0);
        }

        float sc[4][4];
#pragma unroll
        for (int nt = 0; nt < 4; ++nt) {
            const float bias = mb[l16 + nt * 16];
#pragma unroll
            for (int r = 0; r < 4; ++r)
                sc[nt][r] = Sacc[nt][r] * 0.125f + bias;
        }

        float tmax[4];
#pragma unroll
        for (int r = 0; r < 4; ++r)
            tmax[r] = fmaxf(fmaxf(sc[0][r], sc[1][r]), fmaxf(sc[2][r], sc[3][r]));
#pragma unroll
        for (int m = 1; m < 16; m <<= 1) {
#pragma unroll
            for (int r = 0; r < 4; ++r)
                tmax[r] = fmaxf(tmax[r], __shfl_xor(tmax[r], m));
        }
        float alpha[4];
#pragma unroll
        for (int r = 0; r < 4; ++r) {
            const float mn = fmaxf(mrow[r], tmax[r]);
            alpha[r] = __expf(mrow[r] - mn);
            mrow[r]  = mn;
            lrow[r] *= alpha[r];
        }
#pragma unroll
        for (int dt = 0; dt < 4; ++dt)
#pragma unroll
            for (int r = 0; r < 4; ++r) O[dt][r] *= alpha[r];

        float rsum[4] = {0.f, 0.f, 0.f, 0.f};
#pragma unroll
        for (int nt = 0; nt < 4; ++nt) {
#pragma unroll
            for (int r = 0; r < 4; ++r) {
                const float p = __expf(sc[nt][r] - mrow[r]);
                rsum[r] += p;
                Ps[wave][quad * 4 + r][l16 + nt * 16] = (_Float16)p;
            }
        }
#pragma unroll
        for (int m = 1; m < 16; m <<= 1) {
#pragma unroll
            for (int r = 0; r < 4; ++r) rsum[r] += __shfl_xor(rsum[r], m);
        }
#pragma unroll
        for (int r = 0; r < 4; ++r) lrow[r] += rsum[r];

        __syncthreads(); // quad-crossing Ps writes visible before A-frag reads

        half8 pa0 = *(const half8*)&Ps[wave][l16][quad * 8];
        half8 pa1 = *(const half8*)&Ps[wave][l16][quad * 8 + 32];
#pragma unroll
        for (int dt = 0; dt < 4; ++dt) {
            half8 vb0 = *(const half8*)&Vt[dt * 16 + l16][quad * 8];
            half8 vb1 = *(const half8*)&Vt[dt * 16 + l16][quad * 8 + 32];
            O[dt] = __builtin_amdgcn_mfma_f32_16x16x32_f16(pa0, vb0, O[dt], 0, 0, 0);
            O[dt] = __builtin_amdgcn_mfma_f32_16x16x32_f16(pa1, vb1, O[dt], 0, 0, 0);
        }
    }

#pragma unroll
    for (int r = 0; r < 4; ++r) {
        const float inv = 1.f / lrow[r];
        const int q = q0 + wave * 16 + quad * 4 + r;
        float* op = out + ((size_t)(b * SS + q)) * DIMD + h * DH;
#pragma unroll
        for (int dt = 0; dt < 4; ++dt)
            op[dt * 16 + l16] = O[dt][r] * inv;
    }
}

extern "C" void kernel_launch(void* const* d_in, const int* in_sizes, int n_in,
                              void* d_out, int out_size, void* d_ws, size_t ws_size,
                              hipStream_t stream) {
    const float* x  = (const float*)d_in[0];
    const int* mask = (const int*)d_in[1];
    const float* Wq = (const float*)d_in[2];
    const float* bq = (const float*)d_in[3];
    const float* Wk = (const float*)d_in[4];
    const float* bk = (const float*)d_in[5];
    const float* Wv = (const float*)d_in[6];
    const float* bv = (const float*)d_in[7];
    float* out = (float*)d_out;

    // workspace: xh (8.4MB) | Wt (6.3MB) | Q,K,V fp16 (8.4MB each) = ~40MB
    _Float16* xh = (_Float16*)d_ws;
    _Float16* Wt = xh + (size_t)M_TOTAL * DIMD;
    _Float16* Q  = Wt + (size_t)3 * DIMD * DIMD;
    _Float16* K  = Q + (size_t)M_TOTAL * DIMD;
    _Float16* V  = K + (size_t)M_TOTAL * DIMD;

    cvt_x_kernel<<<M_TOTAL * DIMD / 1024, 256, 0, stream>>>(x, xh);
    cvt_wt_kernel<<<dim3(32, 32, 3), 256, 0, stream>>>(Wq, Wk, Wv, Wt);
    proj_gemm<<<dim3(M_TOTAL / 128, DIMD / 128, 3), 256, 0, stream>>>(
        xh, Wt, bq, bk, bv, Q, K, V);
    attn_kernel<<<dim3(SS / 64, BB * NH), 256, 0, stream>>>(Q, K, V, mask, out);
}

// Round 6
// 221.376 us; speedup vs baseline: 7.3000x; 1.1756x over previous
//
#include <hip/hip_runtime.h>
#include <math.h>

#define DIMD 1024
#define NH 16
#define DH 64
#define BB 2
#define SS 2048
#define M_TOTAL (BB * SS) /* 4096 */

typedef _Float16 half8 __attribute__((ext_vector_type(8)));
typedef _Float16 half4v __attribute__((ext_vector_type(4)));
typedef __fp16 fp16x2 __attribute__((ext_vector_type(2))); // cvt_pkrtz result type
typedef float floatx4 __attribute__((ext_vector_type(4)));
typedef float floatx16 __attribute__((ext_vector_type(16)));

// Q is pre-scaled by 1/sqrt(Dh) * log2(e) at proj time -> scores are in the
// exp2 domain and the attn kernel needs no per-score multiply.
#define QSCALE 0.18033688011112042f

// async 16B global->LDS. LDS dest is wave-uniform base + lane*16 (m104/m108).
__device__ __forceinline__ void load16_to_lds(const void* g, void* l) {
    __builtin_amdgcn_global_load_lds(
        (const __attribute__((address_space(1))) void*)g,
        (__attribute__((address_space(3))) void*)l, 16, 0, 0);
}

// ---------------------------------------------------------------------------
// x fp32 -> fp16, same [m][k] layout.
// ---------------------------------------------------------------------------
__global__ __launch_bounds__(256) void cvt_x_kernel(
    const float* __restrict__ x, _Float16* __restrict__ xh)
{
    const int i = blockIdx.x * 256 + threadIdx.x; // float4 index
    float4 v = ((const float4*)x)[i];
    half4v h = {(_Float16)v.x, (_Float16)v.y, (_Float16)v.z, (_Float16)v.w};
    *(half4v*)&xh[(size_t)i * 4] = h;
}

// ---------------------------------------------------------------------------
// W [k][n] fp32 -> Wt [n][k] fp16 (transpose via LDS 32x32 tile).
// ---------------------------------------------------------------------------
__global__ __launch_bounds__(256) void cvt_wt_kernel(
    const float* __restrict__ Wq, const float* __restrict__ Wk,
    const float* __restrict__ Wv, _Float16* __restrict__ Wt)
{
    const float* W = blockIdx.z == 0 ? Wq : (blockIdx.z == 1 ? Wk : Wv);
    _Float16* o = Wt + (size_t)blockIdx.z * DIMD * DIMD;
    __shared__ _Float16 Ls[32][34];
    const int k0 = blockIdx.x * 32, n0 = blockIdx.y * 32;
    const int tid = threadIdx.x;
    const int r = tid >> 3, c4 = (tid & 7) * 4;

    float4 v = *(const float4*)&W[(size_t)(k0 + r) * DIMD + n0 + c4];
    Ls[r][c4 + 0] = (_Float16)v.x;
    Ls[r][c4 + 1] = (_Float16)v.y;
    Ls[r][c4 + 2] = (_Float16)v.z;
    Ls[r][c4 + 3] = (_Float16)v.w;
    __syncthreads();

    half4v h = {Ls[c4 + 0][r], Ls[c4 + 1][r], Ls[c4 + 2][r], Ls[c4 + 3][r]};
    *(half4v*)&o[(size_t)(n0 + r) * DIMD + k0 + c4] = h;
}

// ---------------------------------------------------------------------------
// MFMA projection GEMM (unchanged from R4 except Q-scale fold):
// C = xh @ Wt^T (+bias) [*QSCALE for Q], scattered to (B,H,S,Dh) fp16.
// ---------------------------------------------------------------------------
__global__ __launch_bounds__(256) void proj_gemm(
    const _Float16* __restrict__ xh, const _Float16* __restrict__ Wt,
    const float* __restrict__ bq, const float* __restrict__ bk,
    const float* __restrict__ bv,
    _Float16* __restrict__ Q, _Float16* __restrict__ K, _Float16* __restrict__ V)
{
    const int z = blockIdx.z;
    const float* bias = z == 0 ? bq : (z == 1 ? bk : bv);
    _Float16* out = z == 0 ? Q : (z == 1 ? K : V);
    const _Float16* Wz = Wt + (size_t)z * DIMD * DIMD;
    const float oscale = (z == 0) ? QSCALE : 1.0f;

    __shared__ _Float16 Ah[128 * 64];
    __shared__ _Float16 Bh[128 * 64];

    const int tid = threadIdx.x;
    const int wave = tid >> 6, lane = tid & 63;
    const int quad = lane >> 4, l16 = lane & 15;
    const int wm = (wave >> 1) * 64, wn = (wave & 1) * 64;
    const int m0 = blockIdx.x * 128, n0 = blockIdx.y * 128;
    const int sw = l16 & 7;

    floatx4 acc[4][4];
#pragma unroll
    for (int i = 0; i < 4; ++i)
#pragma unroll
        for (int j = 0; j < 4; ++j) acc[i][j] = (floatx4){0.f, 0.f, 0.f, 0.f};

    for (int k0 = 0; k0 < DIMD; k0 += 64) {
        __syncthreads();
#pragma unroll
        for (int it = 0; it < 4; ++it) {
            const int u = it * 256 + tid;
            const int row = u >> 3;
            const int gc = (u & 7) ^ (row & 7);
            load16_to_lds(&xh[(size_t)(m0 + row) * DIMD + k0 + gc * 8],
                          &Ah[(size_t)(it * 256 + wave * 64) * 8]);
        }
#pragma unroll
        for (int it = 0; it < 4; ++it) {
            const int u = it * 256 + tid;
            const int row = u >> 3;
            const int gc = (u & 7) ^ (row & 7);
            load16_to_lds(&Wz[(size_t)(n0 + row) * DIMD + k0 + gc * 8],
                          &Bh[(size_t)(it * 256 + wave * 64) * 8]);
        }
        __syncthreads();

#pragma unroll
        for (int kc = 0; kc < 2; ++kc) {
            const int coff = ((quad + kc * 4) ^ sw) * 8;
            half8 af[4], bf[4];
#pragma unroll
            for (int mt = 0; mt < 4; ++mt)
                af[mt] = *(const half8*)&Ah[(wm + mt * 16 + l16) * 64 + coff];
#pragma unroll
            for (int nt = 0; nt < 4; ++nt)
                bf[nt] = *(const half8*)&Bh[(wn + nt * 16 + l16) * 64 + coff];
#pragma unroll
            for (int mt = 0; mt < 4; ++mt)
#pragma unroll
                for (int nt = 0; nt < 4; ++nt)
                    acc[mt][nt] = __builtin_amdgcn_mfma_f32_16x16x32_f16(
                        af[mt], bf[nt], acc[mt][nt], 0, 0, 0);
        }
    }

#pragma unroll
    for (int nt = 0; nt < 4; ++nt) {
        const int n = n0 + wn + nt * 16 + l16;
        const float bn = bias[n];
        const int h = n >> 6, d = n & 63;
#pragma unroll
        for (int mt = 0; mt < 4; ++mt) {
#pragma unroll
            for (int r = 0; r < 4; ++r) {
                const int m = m0 + wm + mt * 16 + quad * 4 + r;
                const int b = m >> 11, s = m & 2047;
                out[((((size_t)b * NH + h) * SS + s) << 6) + d] =
                    (_Float16)((acc[mt][nt][r] + bn) * oscale);
            }
        }
    }
}

// ---------------------------------------------------------------------------
// MFMA flash attention, transposed formulation, 32x32x16 shapes.
//   S^T = K·Q^T   (A = K[t][d] from LDS, B = Q^T in persistent regs)
//   O^T = V^T·P^T (A = V^T[d][t] from LDS, B = P^T built in-register)
// C/D 32x32 layout (m74/m101): col = lane&31, row = (reg&3)+8*(reg>>2)+4*(lane>>5)
// A: m = lane&31, k = 8*(lane>>5)+j.  B: k = 8*(lane>>5)+j, n = lane&31.
// col = q for both S^T and O^T -> softmax state (m,l,alpha) is lane-resident;
// reductions are in-lane + one shfl_xor(32). P^T -> B-frag via pkrtz + 2
// shfl_xor(32) per k-step (no LDS, no barrier).
// Mask: per-tile 64-bit ballot; P zeroed per-register (exp(-10000)==0 in ref).
// Double-buffered K/V^T LDS, one barrier per tile, prefetch-before-compute.
// grid = (S/128, B*H), block = 256 (4 waves x 32 q).
// ---------------------------------------------------------------------------
__global__ __launch_bounds__(256, 2) void attn_kernel(
    const _Float16* __restrict__ Q, const _Float16* __restrict__ K,
    const _Float16* __restrict__ V, const int* __restrict__ mask,
    float* __restrict__ out)
{
    __shared__ __align__(16) char smem[49152]; // Ks[2]:16K | Vt[2]:16K | Qs:16K
    const int bh = blockIdx.y, b = bh >> 4, h = bh & 15;
    const int q0 = blockIdx.x * 128;
    const int tid = threadIdx.x, wave = tid >> 6, lane = tid & 63;
    const int hi = lane >> 5, l31 = lane & 31;

    const _Float16* Qb = Q + (size_t)bh * SS * DH;
    const _Float16* Kb = K + (size_t)bh * SS * DH;
    const _Float16* Vb = V + (size_t)bh * SS * DH;

    _Float16* Qs = (_Float16*)(smem + 32768);

    // ---- stage Q (128 rows x 64, swizzled chunks) ----
#pragma unroll
    for (int it = 0; it < 4; ++it) {
        const int u = it * 256 + tid;
        const int row = u >> 3, gc = (u & 7) ^ (row & 7);
        load16_to_lds(&Qb[(size_t)(q0 + row) * DH + gc * 8],
                      Qs + (size_t)(it * 256 + wave * 64) * 8);
    }
    // ---- stage K/V^T tile 0 into buffer 0 ----
    {
        _Float16* KsB = (_Float16*)smem;
#pragma unroll
        for (int it = 0; it < 2; ++it) {
            const int u = it * 256 + tid;
            const int row = u >> 3, gc = (u & 7) ^ (row & 7);
            load16_to_lds(&Kb[(size_t)row * DH + gc * 8],
                          KsB + (size_t)(it * 256 + wave * 64) * 8);
        }
        _Float16* VtB = (_Float16*)(smem + 16384);
#pragma unroll
        for (int it = 0; it < 2; ++it) {
            const int idx = it * 256 + tid;
            const int t = idx & 63, d0 = (idx >> 6) * 8;
            union { uint4 u4; _Float16 hv[8]; } tmp;
            tmp.u4 = *(const uint4*)&Vb[(size_t)t * DH + d0];
#pragma unroll
            for (int k2 = 0; k2 < 8; ++k2) {
                const int d = d0 + k2;
                VtB[d * 64 + (((t >> 3) ^ (d & 7)) << 3) + (t & 7)] = tmp.hv[k2];
            }
        }
    }
    __syncthreads();

    // ---- persistent Q B-fragments (B[k=8hi+j][n=q]) ----
    half8 qf[4];
#pragma unroll
    for (int ks = 0; ks < 4; ++ks) {
        const int row = wave * 32 + l31, c = 2 * ks + hi, slot = c ^ (row & 7);
        qf[ks] = *(const half8*)&Qs[row * 64 + slot * 8];
    }

    floatx16 O0, O1;
#pragma unroll
    for (int r = 0; r < 16; ++r) { O0[r] = 0.f; O1[r] = 0.f; }
    float m = -1e30f, l = 0.f;

    for (int i = 0; i < 32; ++i) {
        const int buf = i & 1;
        const int t0 = i * 64;

        // ---- prefetch next tile into the other buffer (async, pre-compute) --
        if (i + 1 < 32) {
            const int nb = buf ^ 1, nt0 = t0 + 64;
            _Float16* KsN = (_Float16*)(smem + nb * 8192);
#pragma unroll
            for (int it = 0; it < 2; ++it) {
                const int u = it * 256 + tid;
                const int row = u >> 3, gc = (u & 7) ^ (row & 7);
                load16_to_lds(&Kb[(size_t)(nt0 + row) * DH + gc * 8],
                              KsN + (size_t)(it * 256 + wave * 64) * 8);
            }
            _Float16* VtN = (_Float16*)(smem + 16384 + nb * 8192);
#pragma unroll
            for (int it = 0; it < 2; ++it) {
                const int idx = it * 256 + tid;
                const int t = idx & 63, d0 = (idx >> 6) * 8;
                union { uint4 u4; _Float16 hv[8]; } tmp;
                tmp.u4 = *(const uint4*)&Vb[(size_t)(nt0 + t) * DH + d0];
#pragma unroll
                for (int k2 = 0; k2 < 8; ++k2) {
                    const int d = d0 + k2;
                    VtN[d * 64 + (((t >> 3) ^ (d & 7)) << 3) + (t & 7)] = tmp.hv[k2];
                }
            }
        }

        const _Float16* KsB = (const _Float16*)(smem + buf * 8192);
        const _Float16* VtB = (const _Float16*)(smem + 16384 + buf * 8192);

        // ---- mask bits for this tile (t-local bit index) ----
        const int mk = mask[b * SS + t0 + lane];
        const unsigned long long bm = __ballot(mk != 0);
        const unsigned long long sh = bm >> (4 * hi);
        const unsigned int wlo = (unsigned int)sh;
        const unsigned int whi = (unsigned int)(sh >> 32);

        // ---- QK^T: S^T[t][q], 2 m-tiles x 4 k-steps ----
        floatx16 S0, S1;
#pragma unroll
        for (int r = 0; r < 16; ++r) { S0[r] = 0.f; S1[r] = 0.f; }
#pragma unroll
        for (int ks = 0; ks < 4; ++ks) {
            const int c = 2 * ks + hi;
            const int r0 = l31, r1 = 32 + l31;
            half8 a0 = *(const half8*)&KsB[r0 * 64 + ((c ^ (r0 & 7)) << 3)];
            half8 a1 = *(const half8*)&KsB[r1 * 64 + ((c ^ (r1 & 7)) << 3)];
            S0 = __builtin_amdgcn_mfma_f32_32x32x16_f16(a0, qf[ks], S0, 0, 0, 0);
            S1 = __builtin_amdgcn_mfma_f32_32x32x16_f16(a1, qf[ks], S1, 0, 0, 0);
        }

        // ---- online softmax, lane-resident (base-2 domain) ----
        float tmax = -1e30f;
#pragma unroll
        for (int r = 0; r < 16; ++r)
            tmax = fmaxf(tmax, fmaxf(S0[r], S1[r]));
        tmax = fmaxf(tmax, __shfl_xor(tmax, 32));
        const float mn = fmaxf(m, tmax);
        const float alpha = exp2f(m - mn);
        m = mn;

        float p0[16], p1[16];
        float lsum = 0.f;
#pragma unroll
        for (int r = 0; r < 16; ++r) {
            const int base = (r & 3) + 8 * (r >> 2);
            float e0 = exp2f(S0[r] - m);
            float e1 = exp2f(S1[r] - m);
            e0 = ((wlo >> base) & 1) ? e0 : 0.f;
            e1 = ((whi >> base) & 1) ? e1 : 0.f;
            p0[r] = e0; p1[r] = e1;
            lsum += e0 + e1;
        }
        lsum += __shfl_xor(lsum, 32);
        l = l * alpha + lsum;
#pragma unroll
        for (int r = 0; r < 16; ++r) { O0[r] *= alpha; O1[r] *= alpha; }

        // ---- pack P^T to fp16 pairs ----
        unsigned int pk0[8], pk1[8];
#pragma unroll
        for (int j = 0; j < 8; ++j) {
            union { fp16x2 hv; unsigned int u; } cv;
            cv.hv = __builtin_amdgcn_cvt_pkrtz(p0[2 * j], p0[2 * j + 1]);
            pk0[j] = cv.u;
            cv.hv = __builtin_amdgcn_cvt_pkrtz(p1[2 * j], p1[2 * j + 1]);
            pk1[j] = cv.u;
        }

        // ---- PV: O^T += V^T · P^T; P B-frag assembled via shfl_xor(32) ----
#pragma unroll
        for (int ks = 0; ks < 4; ++ks) {
            const int k1 = ks & 1;
            const unsigned int* pk = (ks < 2) ? pk0 : pk1;
            const unsigned int a0 = pk[4 * k1 + 0], a1 = pk[4 * k1 + 1];
            const unsigned int b0 = pk[4 * k1 + 2], b1 = pk[4 * k1 + 3];
            const unsigned int s0 = hi ? a0 : b0, s1 = hi ? a1 : b1;
            const unsigned int r0v = __shfl_xor(s0, 32);
            const unsigned int r1v = __shfl_xor(s1, 32);
            union { unsigned int u[4]; half8 hv; } bf;
            bf.u[0] = hi ? r0v : a0;
            bf.u[1] = hi ? r1v : a1;
            bf.u[2] = hi ? b0 : r0v;
            bf.u[3] = hi ? b1 : r1v;
            const int c = 2 * ks + hi;
            const int rd0 = l31, rd1 = 32 + l31;
            half8 v0 = *(const half8*)&VtB[rd0 * 64 + ((c ^ (rd0 & 7)) << 3)];
            half8 v1 = *(const half8*)&VtB[rd1 * 64 + ((c ^ (rd1 & 7)) << 3)];
            O0 = __builtin_amdgcn_mfma_f32_32x32x16_f16(v0, bf.hv, O0, 0, 0, 0);
            O1 = __builtin_amdgcn_mfma_f32_32x32x16_f16(v1, bf.hv, O1, 0, 0, 0);
        }

        __syncthreads(); // next buffer staged by all + this buffer's reads done
    }

    // ---- epilogue: O^T/l -> LDS transpose (per-wave region) -> coalesced out
    const float inv = 1.f / l;
    float* Ob = (float*)smem + wave * (32 * 68);
#pragma unroll
    for (int r = 0; r < 16; ++r) {
        const int dbase = (r & 3) + 8 * (r >> 2) + 4 * hi;
        Ob[l31 * 68 + dbase] = O0[r] * inv;
        Ob[l31 * 68 + 32 + dbase] = O1[r] * inv;
    }
    __syncthreads(); // cross-lane LDS visibility before transpose reads

    const int qq = lane >> 1, part = lane & 1;
    float* op = out + ((size_t)(b * SS + q0 + wave * 32 + qq)) * DIMD
              + h * DH + part * 32;
#pragma unroll
    for (int j = 0; j < 8; ++j)
        *(float4*)&op[j * 4] = *(const float4*)&Ob[qq * 68 + part * 32 + j * 4];
}

extern "C" void kernel_launch(void* const* d_in, const int* in_sizes, int n_in,
                              void* d_out, int out_size, void* d_ws, size_t ws_size,
                              hipStream_t stream) {
    const float* x  = (const float*)d_in[0];
    const int* mask = (const int*)d_in[1];
    const float* Wq = (const float*)d_in[2];
    const float* bq = (const float*)d_in[3];
    const float* Wk = (const float*)d_in[4];
    const float* bk = (const float*)d_in[5];
    const float* Wv = (const float*)d_in[6];
    const float* bv = (const float*)d_in[7];
    float* out = (float*)d_out;

    _Float16* xh = (_Float16*)d_ws;
    _Float16* Wt = xh + (size_t)M_TOTAL * DIMD;
    _Float16* Q  = Wt + (size_t)3 * DIMD * DIMD;
    _Float16* K  = Q + (size_t)M_TOTAL * DIMD;
    _Float16* V  = K + (size_t)M_TOTAL * DIMD;

    cvt_x_kernel<<<M_TOTAL * DIMD / 1024, 256, 0, stream>>>(x, xh);
    cvt_wt_kernel<<<dim3(32, 32, 3), 256, 0, stream>>>(Wq, Wk, Wv, Wt);
    proj_gemm<<<dim3(M_TOTAL / 128, DIMD / 128, 3), 256, 0, stream>>>(
        xh, Wt, bq, bk, bv, Q, K, V);
    attn_kernel<<<dim3(SS / 128, BB * NH), 256, 0, stream>>>(Q, K, V, mask, out);
}

// Round 7
// 181.396 us; speedup vs baseline: 8.9089x; 1.2204x over previous
//
#include <hip/hip_runtime.h>
#include <math.h>

#define DIMD 1024
#define NH 16
#define DH 64
#define BB 2
#define SS 2048
#define M_TOTAL (BB * SS) /* 4096 */

typedef _Float16 half8 __attribute__((ext_vector_type(8)));
typedef _Float16 half4v __attribute__((ext_vector_type(4)));
typedef __fp16 fp16x2 __attribute__((ext_vector_type(2))); // cvt_pkrtz result type
typedef float floatx4 __attribute__((ext_vector_type(4)));
typedef float floatx16 __attribute__((ext_vector_type(16)));

// Q is pre-scaled by 1/sqrt(Dh) * log2(e) at proj time -> scores are in the
// exp2 domain and the attn kernel needs no per-score multiply.
#define QSCALE 0.18033688011112042f

// async 16B global->LDS. LDS dest is wave-uniform base + lane*16 (m104/m108).
__device__ __forceinline__ void load16_to_lds(const void* g, void* l) {
    __builtin_amdgcn_global_load_lds(
        (const __attribute__((address_space(1))) void*)g,
        (__attribute__((address_space(3))) void*)l, 16, 0, 0);
}

// ---------------------------------------------------------------------------
// Mask compaction scan: per b, pos[b*SS+s] = compact index if mask else -1;
// nvalid[b] = count. Masked-out keys contribute exactly 0 to softmax
// (exp(-10000-m) underflows in fp32), so dropping them is exact.
// grid = (B), block = 64 (one wave).
// ---------------------------------------------------------------------------
__global__ __launch_bounds__(64) void scan_mask_kernel(
    const int* __restrict__ mask, int* __restrict__ pos, int* __restrict__ nvalid)
{
    const int b = blockIdx.x, lane = threadIdx.x;
    int base = 0;
    const unsigned long long lanemask = (lane == 63)
        ? 0x7fffffffffffffffull : ((1ull << lane) - 1ull);
    for (int c = 0; c < SS / 64; ++c) {
        const int mv = mask[b * SS + c * 64 + lane];
        const unsigned long long bm = __ballot(mv != 0);
        const int pc = __popcll(bm & lanemask);
        pos[b * SS + c * 64 + lane] = mv ? (base + pc) : -1;
        base += __popcll(bm);
    }
    if (lane == 0) nvalid[b] = base;
}

// ---------------------------------------------------------------------------
// x fp32 -> fp16, same [m][k] layout.
// ---------------------------------------------------------------------------
__global__ __launch_bounds__(256) void cvt_x_kernel(
    const float* __restrict__ x, _Float16* __restrict__ xh)
{
    const int i = blockIdx.x * 256 + threadIdx.x; // float4 index
    float4 v = ((const float4*)x)[i];
    half4v h = {(_Float16)v.x, (_Float16)v.y, (_Float16)v.z, (_Float16)v.w};
    *(half4v*)&xh[(size_t)i * 4] = h;
}

// ---------------------------------------------------------------------------
// W [k][n] fp32 -> Wt [n][k] fp16 (transpose via LDS 32x32 tile).
// ---------------------------------------------------------------------------
__global__ __launch_bounds__(256) void cvt_wt_kernel(
    const float* __restrict__ Wq, const float* __restrict__ Wk,
    const float* __restrict__ Wv, _Float16* __restrict__ Wt)
{
    const float* W = blockIdx.z == 0 ? Wq : (blockIdx.z == 1 ? Wk : Wv);
    _Float16* o = Wt + (size_t)blockIdx.z * DIMD * DIMD;
    __shared__ _Float16 Ls[32][34];
    const int k0 = blockIdx.x * 32, n0 = blockIdx.y * 32;
    const int tid = threadIdx.x;
    const int r = tid >> 3, c4 = (tid & 7) * 4;

    float4 v = *(const float4*)&W[(size_t)(k0 + r) * DIMD + n0 + c4];
    Ls[r][c4 + 0] = (_Float16)v.x;
    Ls[r][c4 + 1] = (_Float16)v.y;
    Ls[r][c4 + 2] = (_Float16)v.z;
    Ls[r][c4 + 3] = (_Float16)v.w;
    __syncthreads();

    half4v h = {Ls[c4 + 0][r], Ls[c4 + 1][r], Ls[c4 + 2][r], Ls[c4 + 3][r]};
    *(half4v*)&o[(size_t)(n0 + r) * DIMD + k0 + c4] = h;
}

// ---------------------------------------------------------------------------
// MFMA projection GEMM. Q -> [bh][s][d] (*QSCALE). K -> [bh][t'][d] with t'
// the compacted key index (masked-out rows dropped). V -> transposed
// [bh][d][t'] so the attn kernel can DMA-stage V^T with zero VALU transpose.
// ---------------------------------------------------------------------------
__global__ __launch_bounds__(256) void proj_gemm(
    const _Float16* __restrict__ xh, const _Float16* __restrict__ Wt,
    const float* __restrict__ bq, const float* __restrict__ bk,
    const float* __restrict__ bv, const int* __restrict__ pos,
    _Float16* __restrict__ Q, _Float16* __restrict__ K, _Float16* __restrict__ Vt)
{
    const int z = blockIdx.z;
    const float* bias = z == 0 ? bq : (z == 1 ? bk : bv);
    const _Float16* Wz = Wt + (size_t)z * DIMD * DIMD;

    __shared__ _Float16 Ah[128 * 64];
    __shared__ _Float16 Bh[128 * 64];

    const int tid = threadIdx.x;
    const int wave = tid >> 6, lane = tid & 63;
    const int quad = lane >> 4, l16 = lane & 15;
    const int wm = (wave >> 1) * 64, wn = (wave & 1) * 64;
    const int m0 = blockIdx.x * 128, n0 = blockIdx.y * 128;
    const int sw = l16 & 7;

    floatx4 acc[4][4];
#pragma unroll
    for (int i = 0; i < 4; ++i)
#pragma unroll
        for (int j = 0; j < 4; ++j) acc[i][j] = (floatx4){0.f, 0.f, 0.f, 0.f};

    for (int k0 = 0; k0 < DIMD; k0 += 64) {
        __syncthreads();
#pragma unroll
        for (int it = 0; it < 4; ++it) {
            const int u = it * 256 + tid;
            const int row = u >> 3;
            const int gc = (u & 7) ^ (row & 7);
            load16_to_lds(&xh[(size_t)(m0 + row) * DIMD + k0 + gc * 8],
                          &Ah[(size_t)(it * 256 + wave * 64) * 8]);
        }
#pragma unroll
        for (int it = 0; it < 4; ++it) {
            const int u = it * 256 + tid;
            const int row = u >> 3;
            const int gc = (u & 7) ^ (row & 7);
            load16_to_lds(&Wz[(size_t)(n0 + row) * DIMD + k0 + gc * 8],
                          &Bh[(size_t)(it * 256 + wave * 64) * 8]);
        }
        __syncthreads();

#pragma unroll
        for (int kc = 0; kc < 2; ++kc) {
            const int coff = ((quad + kc * 4) ^ sw) * 8;
            half8 af[4], bf[4];
#pragma unroll
            for (int mt = 0; mt < 4; ++mt)
                af[mt] = *(const half8*)&Ah[(wm + mt * 16 + l16) * 64 + coff];
#pragma unroll
            for (int nt = 0; nt < 4; ++nt)
                bf[nt] = *(const half8*)&Bh[(wn + nt * 16 + l16) * 64 + coff];
#pragma unroll
            for (int mt = 0; mt < 4; ++mt)
#pragma unroll
                for (int nt = 0; nt < 4; ++nt)
                    acc[mt][nt] = __builtin_amdgcn_mfma_f32_16x16x32_f16(
                        af[mt], bf[nt], acc[mt][nt], 0, 0, 0);
        }
    }

    // row metadata (independent of nt)
    int prr[4][4], brow[4][4], srow[4][4];
#pragma unroll
    for (int mt = 0; mt < 4; ++mt)
#pragma unroll
        for (int r = 0; r < 4; ++r) {
            const int m = m0 + wm + mt * 16 + quad * 4 + r;
            brow[mt][r] = m >> 11;
            srow[mt][r] = m & 2047;
            prr[mt][r] = (z == 0) ? 0 : pos[m];
        }

#pragma unroll
    for (int nt = 0; nt < 4; ++nt) {
        const int n = n0 + wn + nt * 16 + l16;
        const float bn = bias[n];
        const int h = n >> 6, d = n & 63;
#pragma unroll
        for (int mt = 0; mt < 4; ++mt) {
#pragma unroll
            for (int r = 0; r < 4; ++r) {
                const int b = brow[mt][r];
                const _Float16 val = (_Float16)((acc[mt][nt][r] + bn) *
                                                (z == 0 ? QSCALE : 1.0f));
                if (z == 0) {
                    Q[((((size_t)b * NH + h) * SS + srow[mt][r]) << 6) + d] = val;
                } else if (prr[mt][r] >= 0) {
                    if (z == 1)
                        K[((((size_t)b * NH + h) * SS + prr[mt][r]) << 6) + d] = val;
                    else
                        Vt[(((size_t)b * NH + h) * DH + d) * SS + prr[mt][r]] = val;
                }
            }
        }
    }
}

// ---------------------------------------------------------------------------
// MFMA flash attention over COMPACTED keys (no mask ops in the hot loop).
//   S^T = K·Q^T   (A = K[t][d] from LDS, B = Q^T in persistent regs)
//   O^T = V^T·P^T (A = V^T[d][t] from LDS, B = P^T built in-register)
// C/D 32x32: col=lane&31, row=(reg&3)+8*(reg>>2)+4*(lane>>5).
// A: m=lane&31, k=8*(lane>>5)+j.  B: k=8*(lane>>5)+j, n=lane&31.
// K and V^T both staged via global_load_lds DMA (XOR-swizzled chunks).
// Only the final partial tile applies a validity select (before max!).
// grid = (S/128, B*H), block = 256 (4 waves x 32 q).
// ---------------------------------------------------------------------------
__global__ __launch_bounds__(256, 2) void attn_kernel(
    const _Float16* __restrict__ Q, const _Float16* __restrict__ K,
    const _Float16* __restrict__ Vt, const int* __restrict__ nvalid,
    float* __restrict__ out)
{
    __shared__ __align__(16) char smem[34816]; // Ks[2]:16K|Vt[2]:16K; epi 34K
    const int bh = blockIdx.y, b = bh >> 4, h = bh & 15;
    const int q0 = blockIdx.x * 128;
    const int tid = threadIdx.x, wave = tid >> 6, lane = tid & 63;
    const int hi = lane >> 5, l31 = lane & 31;

    const _Float16* Qb = Q + (size_t)bh * SS * DH;
    const _Float16* Kb = K + (size_t)bh * SS * DH;
    const _Float16* Vtb = Vt + (size_t)bh * DH * SS;

    const int nv = nvalid[b];
    const int ntiles = (nv + 63) >> 6;

    // ---- persistent Q B-fragments, direct from global (16B coalesced) ----
    half8 qf[4];
#pragma unroll
    for (int ks = 0; ks < 4; ++ks)
        qf[ks] = *(const half8*)&Qb[(size_t)(q0 + wave * 32 + l31) * DH
                                    + ks * 16 + hi * 8];

    // ---- stage K/V^T tile 0 into buffer 0 (pure DMA) ----
#pragma unroll
    for (int it = 0; it < 2; ++it) {
        const int u = it * 256 + tid;
        const int row = u >> 3, gc = (u & 7) ^ (row & 7);
        load16_to_lds(&Kb[(size_t)row * DH + gc * 8],
                      (_Float16*)smem + (size_t)(it * 256 + wave * 64) * 8);
    }
#pragma unroll
    for (int it = 0; it < 2; ++it) {
        const int u = it * 256 + tid;
        const int row = u >> 3, gc = (u & 7) ^ (row & 7);
        load16_to_lds(&Vtb[(size_t)row * SS + gc * 8],
                      (_Float16*)(smem + 16384) + (size_t)(it * 256 + wave * 64) * 8);
    }
    __syncthreads();

    floatx16 O0, O1;
#pragma unroll
    for (int r = 0; r < 16; ++r) { O0[r] = 0.f; O1[r] = 0.f; }
    float m = -1e30f, l = 0.f;

    for (int i = 0; i < ntiles; ++i) {
        const int buf = i & 1;
        const int t0 = i * 64;

        // ---- prefetch next tile into the other buffer (async DMA) ----
        if (i + 1 < ntiles) {
            const int nb = buf ^ 1, nt0 = t0 + 64;
            _Float16* KsN = (_Float16*)(smem + nb * 8192);
#pragma unroll
            for (int it = 0; it < 2; ++it) {
                const int u = it * 256 + tid;
                const int row = u >> 3, gc = (u & 7) ^ (row & 7);
                load16_to_lds(&Kb[(size_t)(nt0 + row) * DH + gc * 8],
                              KsN + (size_t)(it * 256 + wave * 64) * 8);
            }
            _Float16* VtN = (_Float16*)(smem + 16384 + nb * 8192);
#pragma unroll
            for (int it = 0; it < 2; ++it) {
                const int u = it * 256 + tid;
                const int row = u >> 3, gc = (u & 7) ^ (row & 7);
                load16_to_lds(&Vtb[(size_t)row * SS + nt0 + gc * 8],
                              VtN + (size_t)(it * 256 + wave * 64) * 8);
            }
        }

        const _Float16* KsB = (const _Float16*)(smem + buf * 8192);
        const _Float16* VtB = (const _Float16*)(smem + 16384 + buf * 8192);

        // ---- QK^T: S^T[t][q], 2 m-tiles x 4 k-steps ----
        floatx16 S0, S1;
#pragma unroll
        for (int r = 0; r < 16; ++r) { S0[r] = 0.f; S1[r] = 0.f; }
#pragma unroll
        for (int ks = 0; ks < 4; ++ks) {
            const int c = 2 * ks + hi;
            const int r0 = l31, r1 = 32 + l31;
            half8 a0 = *(const half8*)&KsB[r0 * 64 + ((c ^ (r0 & 7)) << 3)];
            half8 a1 = *(const half8*)&KsB[r1 * 64 + ((c ^ (r1 & 7)) << 3)];
            S0 = __builtin_amdgcn_mfma_f32_32x32x16_f16(a0, qf[ks], S0, 0, 0, 0);
            S1 = __builtin_amdgcn_mfma_f32_32x32x16_f16(a1, qf[ks], S1, 0, 0, 0);
        }

        // ---- tail-tile validity select (BEFORE the max reduction) ----
        if (t0 + 64 > nv) {
#pragma unroll
            for (int r = 0; r < 16; ++r) {
                const int tr = (r & 3) + 8 * (r >> 2) + 4 * hi;
                S0[r] = (t0 + tr < nv) ? S0[r] : -1e30f;
                S1[r] = (t0 + 32 + tr < nv) ? S1[r] : -1e30f;
            }
        }

        // ---- online softmax, lane-resident (base-2 domain) ----
        float tmax = -1e30f;
#pragma unroll
        for (int r = 0; r < 16; ++r)
            tmax = fmaxf(tmax, fmaxf(S0[r], S1[r]));
        tmax = fmaxf(tmax, __shfl_xor(tmax, 32));
        const float mn = fmaxf(m, tmax);
        const float alpha = exp2f(m - mn);
        m = mn;

        float p0[16], p1[16];
        float lsum = 0.f;
#pragma unroll
        for (int r = 0; r < 16; ++r) {
            const float e0 = exp2f(S0[r] - m);
            const float e1 = exp2f(S1[r] - m);
            p0[r] = e0; p1[r] = e1;
            lsum += e0 + e1;
        }
        lsum += __shfl_xor(lsum, 32);
        l = l * alpha + lsum;
#pragma unroll
        for (int r = 0; r < 16; ++r) { O0[r] *= alpha; O1[r] *= alpha; }

        // ---- pack P^T to fp16 pairs ----
        unsigned int pk0[8], pk1[8];
#pragma unroll
        for (int j = 0; j < 8; ++j) {
            union { fp16x2 hv; unsigned int u; } cv;
            cv.hv = __builtin_amdgcn_cvt_pkrtz(p0[2 * j], p0[2 * j + 1]);
            pk0[j] = cv.u;
            cv.hv = __builtin_amdgcn_cvt_pkrtz(p1[2 * j], p1[2 * j + 1]);
            pk1[j] = cv.u;
        }

        // ---- PV: O^T += V^T · P^T; P B-frag assembled via shfl_xor(32) ----
#pragma unroll
        for (int ks = 0; ks < 4; ++ks) {
            const int k1 = ks & 1;
            const unsigned int* pk = (ks < 2) ? pk0 : pk1;
            const unsigned int a0 = pk[4 * k1 + 0], a1 = pk[4 * k1 + 1];
            const unsigned int b0 = pk[4 * k1 + 2], b1 = pk[4 * k1 + 3];
            const unsigned int s0 = hi ? a0 : b0, s1 = hi ? a1 : b1;
            const unsigned int r0v = __shfl_xor(s0, 32);
            const unsigned int r1v = __shfl_xor(s1, 32);
            union { unsigned int u[4]; half8 hv; } bf;
            bf.u[0] = hi ? r0v : a0;
            bf.u[1] = hi ? r1v : a1;
            bf.u[2] = hi ? b0 : r0v;
            bf.u[3] = hi ? b1 : r1v;
            const int c = 2 * ks + hi;
            const int rd0 = l31, rd1 = 32 + l31;
            half8 v0 = *(const half8*)&VtB[rd0 * 64 + ((c ^ (rd0 & 7)) << 3)];
            half8 v1 = *(const half8*)&VtB[rd1 * 64 + ((c ^ (rd1 & 7)) << 3)];
            O0 = __builtin_amdgcn_mfma_f32_32x32x16_f16(v0, bf.hv, O0, 0, 0, 0);
            O1 = __builtin_amdgcn_mfma_f32_32x32x16_f16(v1, bf.hv, O1, 0, 0, 0);
        }

        __syncthreads(); // next buffer staged + this buffer's reads done
    }

    // ---- epilogue: O^T/l -> LDS transpose (per-wave region) -> coalesced out
    const float inv = 1.f / l;
    float* Ob = (float*)smem + wave * (32 * 68);
#pragma unroll
    for (int r = 0; r < 16; ++r) {
        const int dbase = (r & 3) + 8 * (r >> 2) + 4 * hi;
        Ob[l31 * 68 + dbase] = O0[r] * inv;
        Ob[l31 * 68 + 32 + dbase] = O1[r] * inv;
    }
    __syncthreads(); // cross-lane LDS visibility before transpose reads

    const int qq = lane >> 1, part = lane & 1;
    float* op = out + ((size_t)(b * SS + q0 + wave * 32 + qq)) * DIMD
              + h * DH + part * 32;
#pragma unroll
    for (int j = 0; j < 8; ++j)
        *(float4*)&op[j * 4] = *(const float4*)&Ob[qq * 68 + part * 32 + j * 4];
}

extern "C" void kernel_launch(void* const* d_in, const int* in_sizes, int n_in,
                              void* d_out, int out_size, void* d_ws, size_t ws_size,
                              hipStream_t stream) {
    const float* x  = (const float*)d_in[0];
    const int* mask = (const int*)d_in[1];
    const float* Wq = (const float*)d_in[2];
    const float* bq = (const float*)d_in[3];
    const float* Wk = (const float*)d_in[4];
    const float* bk = (const float*)d_in[5];
    const float* Wv = (const float*)d_in[6];
    const float* bv = (const float*)d_in[7];
    float* out = (float*)d_out;

    _Float16* xh = (_Float16*)d_ws;                       // 8 MB
    _Float16* Wt = xh + (size_t)M_TOTAL * DIMD;           // 6 MB
    _Float16* Q  = Wt + (size_t)3 * DIMD * DIMD;          // 8 MB
    _Float16* K  = Q + (size_t)M_TOTAL * DIMD;            // 8 MB
    _Float16* Vt = K + (size_t)M_TOTAL * DIMD;            // 8 MB
    int* pos     = (int*)(Vt + (size_t)M_TOTAL * DIMD);   // 16 KB
    int* nvalid  = pos + M_TOTAL;                         // 8 B

    scan_mask_kernel<<<BB, 64, 0, stream>>>(mask, pos, nvalid);
    cvt_x_kernel<<<M_TOTAL * DIMD / 1024, 256, 0, stream>>>(x, xh);
    cvt_wt_kernel<<<dim3(32, 32, 3), 256, 0, stream>>>(Wq, Wk, Wv, Wt);
    proj_gemm<<<dim3(M_TOTAL / 128, DIMD / 128, 3), 256, 0, stream>>>(
        xh, Wt, bq, bk, bv, pos, Q, K, Vt);
    attn_kernel<<<dim3(SS / 128, BB * NH), 256, 0, stream>>>(Q, K, Vt, nvalid, out);
}